// Round 2
// baseline (297.781 us; speedup 1.0000x reference)
//
#include <hip/hip_runtime.h>
#include <hip/hip_bf16.h>
#include <stdint.h>

// Problem: out[m, o] = sum_k x[m,k] * w[o,k] * scale[o] + bias[o]
// M = 4096 (B*S), N = DOUT = 4096, K = DIN = 4096.
// NOTE: harness delivers the int8 weight as int32 (one int per element).
#define M_DIM 4096
#define N_DIM 4096
#define K_DIM 4096

#define BM 128
#define BN 128
#define BK 64
#define KT_TILES (K_DIM / BK)        // 64 k-tiles
#define TILE_ELEMS (BM * BK)         // 8192 bf16 per tile
#define TILE_BYTES (TILE_ELEMS * 2)  // 16384 bytes

typedef unsigned short u16;
typedef __attribute__((ext_vector_type(8))) __bf16 bf16x8;
typedef __attribute__((ext_vector_type(4))) float f32x4;

// ---------------- helpers ----------------

// round-half-up fp32 -> bf16, pack two into a u32 (lo = a, hi = b)
__device__ __forceinline__ uint32_t pack_bf16_rn(float a, float b) {
  uint32_t ua = (__float_as_uint(a) + 0x8000u) >> 16;
  uint32_t ub = (__float_as_uint(b) + 0x8000u) & 0xffff0000u;
  return ua | ub;
}

// two small ints (|v|<=128) -> packed bf16 pair; exact (low 16 bits are 0)
__device__ __forceinline__ uint32_t pack_bf16_int(int a, int b) {
  uint32_t ha = __float_as_uint((float)a) >> 16;
  uint32_t hb = __float_as_uint((float)b) & 0xffff0000u;
  return ha | hb;
}

// async global->LDS, 16 bytes/lane. LDS dest must be wave-uniform base;
// HW adds lane*16. Global src is per-lane.
__device__ __forceinline__ void gload16(const void* g, void* l) {
  __builtin_amdgcn_global_load_lds(
      (__attribute__((address_space(1))) void*)(uintptr_t)g,
      (__attribute__((address_space(3))) void*)l,
      16, 0, 0);
}

// ---------------- convert kernels ----------------
// ws layout (both A and B): [row_tile][k_tile][128 rows][64 cols] bf16,
// with 16B chunks within each 128B row XOR-swizzled: stored_chunk = c ^ (row&7).
// 2M threads, one 16B output chunk (8 elems) each.

__global__ __launch_bounds__(256) void convert_x_kernel(
    const float* __restrict__ x, u16* __restrict__ wsA) {
  uint32_t tid = blockIdx.x * 256u + threadIdx.x;  // [0, 2^21)
  uint32_t c  = tid & 7u;
  uint32_t r  = (tid >> 3) & 127u;
  uint32_t kt = (tid >> 10) & 63u;
  uint32_t mt = tid >> 16;

  const float* src = x + (((size_t)(mt * 128u + r)) << 12) + (kt << 6) + (c << 3);
  float4 f0 = *(const float4*)src;
  float4 f1 = *(const float4*)(src + 4);

  uint4 o;
  o.x = pack_bf16_rn(f0.x, f0.y);
  o.y = pack_bf16_rn(f0.z, f0.w);
  o.z = pack_bf16_rn(f1.x, f1.y);
  o.w = pack_bf16_rn(f1.z, f1.w);

  uint32_t dst_chunk = ((mt * 64u + kt) << 10) + (r << 3) + (c ^ (r & 7u));
  *(uint4*)(wsA + ((size_t)dst_chunk << 3)) = o;
}

__global__ __launch_bounds__(256) void convert_w_kernel(
    const int* __restrict__ w, u16* __restrict__ wsB) {
  uint32_t tid = blockIdx.x * 256u + threadIdx.x;  // [0, 2^21)
  uint32_t c  = tid & 7u;
  uint32_t r  = (tid >> 3) & 127u;
  uint32_t kt = (tid >> 10) & 63u;
  uint32_t nt = tid >> 16;

  // weight row stride = 4096 int32 elements
  const int* src = w + (((size_t)(nt * 128u + r)) << 12) + (kt << 6) + (c << 3);
  int4 i0 = *(const int4*)src;
  int4 i1 = *(const int4*)(src + 4);

  uint4 o;
  o.x = pack_bf16_int(i0.x, i0.y);
  o.y = pack_bf16_int(i0.z, i0.w);
  o.z = pack_bf16_int(i1.x, i1.y);
  o.w = pack_bf16_int(i1.z, i1.w);

  uint32_t dst_chunk = ((nt * 64u + kt) << 10) + (r << 3) + (c ^ (r & 7u));
  *(uint4*)(wsB + ((size_t)dst_chunk << 3)) = o;
}

// ---------------- GEMM ----------------
// 256 threads = 4 waves in 2x2; each wave computes 64x64 = 4x4 frags of 16x16.
// Single-buffered LDS, 2-barrier K-loop (m97 structure), global_load_lds x16B.

__global__ __launch_bounds__(256, 3) void gemm_kernel(
    const u16* __restrict__ wsA, const u16* __restrict__ wsB,
    const float* __restrict__ scale, const float* __restrict__ bias,
    float* __restrict__ out) {
  __shared__ __attribute__((aligned(16))) u16 ldsA[TILE_ELEMS];
  __shared__ __attribute__((aligned(16))) u16 ldsB[TILE_ELEMS];

  const int tid   = threadIdx.x;
  const int lane  = tid & 63;
  const int wid   = tid >> 6;
  const int wr    = wid >> 1;   // wave row (0..1)
  const int wc    = wid & 1;    // wave col (0..1)
  const int nt    = blockIdx.x; // 0..31
  const int mt    = blockIdx.y; // 0..31
  const int r16   = lane & 15;
  const int khalf = lane >> 4;  // 0..3

  f32x4 acc[4][4];
#pragma unroll
  for (int m = 0; m < 4; ++m)
#pragma unroll
    for (int n = 0; n < 4; ++n)
      acc[m][n] = (f32x4){0.f, 0.f, 0.f, 0.f};

  const char* gA = (const char*)(wsA + (size_t)mt * KT_TILES * TILE_ELEMS);
  const char* gB = (const char*)(wsB + (size_t)nt * KT_TILES * TILE_ELEMS);

  // LDS read byte offsets for the kk=0 half; kk=32 half is ^64
  // (chunk base 4 = XOR 4 on the 16B-chunk index).
  int aoff[4], boff[4];
#pragma unroll
  for (int m = 0; m < 4; ++m) {
    int rowa = (wr << 6) + (m << 4) + r16;
    aoff[m] = (rowa << 7) + (((khalf ^ (rowa & 7)) & 7) << 4);
    int rowb = (wc << 6) + (m << 4) + r16;
    boff[m] = (rowb << 7) + (((khalf ^ (rowb & 7)) & 7) << 4);
  }

  for (int kt = 0; kt < KT_TILES; ++kt) {
    __syncthreads();  // previous tile's compute done before overwrite
    const char* srcA = gA + (size_t)kt * TILE_BYTES;
    const char* srcB = gB + (size_t)kt * TILE_BYTES;
#pragma unroll
    for (int r = 0; r < 4; ++r) {
      int o = (r << 12) + (wid << 10);  // 4KB rounds, 1KB per wave
      gload16(srcA + o + lane * 16, (char*)ldsA + o);
      gload16(srcB + o + lane * 16, (char*)ldsB + o);
    }
    __syncthreads();  // staging landed (vmcnt drain at barrier)

    bf16x8 a0[4], b0[4], a1[4], b1[4];
#pragma unroll
    for (int m = 0; m < 4; ++m) {
      a0[m] = *(const bf16x8*)((const char*)ldsA + aoff[m]);
      a1[m] = *(const bf16x8*)((const char*)ldsA + (aoff[m] ^ 64));
      b0[m] = *(const bf16x8*)((const char*)ldsB + boff[m]);
      b1[m] = *(const bf16x8*)((const char*)ldsB + (boff[m] ^ 64));
    }
#pragma unroll
    for (int m = 0; m < 4; ++m)
#pragma unroll
      for (int n = 0; n < 4; ++n)
        acc[m][n] = __builtin_amdgcn_mfma_f32_16x16x32_bf16(a0[m], b0[n], acc[m][n], 0, 0, 0);
#pragma unroll
    for (int m = 0; m < 4; ++m)
#pragma unroll
      for (int n = 0; n < 4; ++n)
        acc[m][n] = __builtin_amdgcn_mfma_f32_16x16x32_bf16(a1[m], b1[n], acc[m][n], 0, 0, 0);
  }

  // Epilogue: out = acc * scale[col] + bias[col]
  // C/D layout (16x16x32): col = lane&15, row = (lane>>4)*4 + reg.
#pragma unroll
  for (int n = 0; n < 4; ++n) {
    int col = (nt << 7) + (wc << 6) + (n << 4) + r16;
    float s  = scale[col];
    float bb = bias[col];
#pragma unroll
    for (int m = 0; m < 4; ++m) {
      int row0 = (mt << 7) + (wr << 6) + (m << 4) + (khalf << 2);
#pragma unroll
      for (int j = 0; j < 4; ++j) {
        out[((size_t)(row0 + j) << 12) + col] = acc[m][n][j] * s + bb;
      }
    }
  }
}

// ---------------- fallback (only if ws too small) ----------------
__global__ __launch_bounds__(256) void fallback_kernel(
    const float* __restrict__ x, const int* __restrict__ w,
    const float* __restrict__ scale, const float* __restrict__ bias,
    float* __restrict__ out) {
  size_t t = (size_t)blockIdx.x * 256 + threadIdx.x;
  if (t >= (size_t)M_DIM * N_DIM) return;
  int col = (int)(t & (N_DIM - 1));
  int row = (int)(t >> 12);
  const float* xr = x + ((size_t)row << 12);
  const int* wr = w + ((size_t)col << 12);
  float acc = 0.f;
  for (int k = 0; k < K_DIM; k += 4) {
    float4 xv = *(const float4*)(xr + k);
    int4 wv = *(const int4*)(wr + k);
    acc += xv.x * (float)wv.x;
    acc += xv.y * (float)wv.y;
    acc += xv.z * (float)wv.z;
    acc += xv.w * (float)wv.w;
  }
  out[t] = acc * scale[col] + bias[col];
}

// ---------------- launch ----------------
extern "C" void kernel_launch(void* const* d_in, const int* in_sizes, int n_in,
                              void* d_out, int out_size, void* d_ws, size_t ws_size,
                              hipStream_t stream) {
  const float* x     = (const float*)d_in[0];
  const int*   w     = (const int*)d_in[1];   // int8 values delivered as int32
  const float* scale = (const float*)d_in[2];
  const float* bias  = (const float*)d_in[3];
  float*       out   = (float*)d_out;

  if (ws_size >= (size_t)64 * 1024 * 1024) {
    u16* wsA = (u16*)d_ws;
    u16* wsB = wsA + (size_t)M_DIM * K_DIM;  // +16M elems = +32MB

    convert_x_kernel<<<8192, 256, 0, stream>>>(x, wsA);
    convert_w_kernel<<<8192, 256, 0, stream>>>(w, wsB);

    dim3 grid(N_DIM / BN, M_DIM / BM);  // (32, 32)
    gemm_kernel<<<grid, 256, 0, stream>>>(wsA, wsB, scale, bias, out);
  } else {
    fallback_kernel<<<(M_DIM * (size_t)N_DIM + 255) / 256, 256, 0, stream>>>(
        x, w, scale, bias, out);
  }
}

// Round 3
// 272.387 us; speedup vs baseline: 1.0932x; 1.0932x over previous
//
#include <hip/hip_runtime.h>
#include <hip/hip_bf16.h>
#include <stdint.h>

// out[m, o] = sum_k x[m,k] * w[o,k] * scale[o] + bias[o]
// M = 4096 (B*S), N = DOUT = 4096, K = DIN = 4096.
// Weight is delivered by the harness as int32 (one int per int8 value).
#define M_DIM 4096
#define N_DIM 4096
#define K_DIM 4096

typedef unsigned short u16;
typedef __attribute__((ext_vector_type(8))) __bf16 bf16x8;
typedef __attribute__((ext_vector_type(4))) float f32x4;

// ---------------- helpers ----------------

__device__ __forceinline__ uint32_t pack_bf16_rn(float a, float b) {
  uint32_t ua = (__float_as_uint(a) + 0x8000u) >> 16;
  uint32_t ub = (__float_as_uint(b) + 0x8000u) & 0xffff0000u;
  return ua | ub;
}

// small ints (|v|<=128) -> bf16 exact
__device__ __forceinline__ uint32_t pack_bf16_int(int a, int b) {
  uint32_t ha = __float_as_uint((float)a) >> 16;
  uint32_t hb = __float_as_uint((float)b) & 0xffff0000u;
  return ha | hb;
}

// async global->LDS, 16B/lane. LDS dest wave-uniform base (+lane*16 in HW).
__device__ __forceinline__ void gload16(const void* g, void* l) {
  __builtin_amdgcn_global_load_lds(
      (__attribute__((address_space(1))) void*)(uintptr_t)g,
      (__attribute__((address_space(3))) void*)l,
      16, 0, 0);
}

// ---------------- fused convert kernel ----------------
// ws tile layout (A and B identical): for supertile ST (256 rows) and k-tile KT
// (64 k): 32KB block at ((ST*64+KT)<<15) bytes:
//   [half h:2][row r:128][chunk:8]*16B, stored chunk index = c ^ (r&7)  (T2 swizzle)
// One thread produces one 16B chunk. tid bits: c3 | r7 | h1 | kt6 | st4  (2M threads/op)
__global__ __launch_bounds__(256) void convert_kernel(
    const float* __restrict__ x, const int* __restrict__ w,
    u16* __restrict__ wsA, u16* __restrict__ wsB) {
  uint32_t bid = blockIdx.x;
  bool isA = bid < 8192;
  uint32_t tid = (isA ? bid : (bid - 8192)) * 256u + threadIdx.x;
  uint32_t c  = tid & 7u;
  uint32_t r  = (tid >> 3) & 127u;
  uint32_t h  = (tid >> 10) & 1u;
  uint32_t kt = (tid >> 11) & 63u;
  uint32_t st = tid >> 17;

  uint32_t row = st * 256u + h * 128u + r;
  uint32_t col = kt * 64u + c * 8u;
  size_t dst16 = ((size_t)(st * 64u + kt) << 11)  // tile = 2048 x 16B
               + (h << 10) + (r << 3) + (c ^ (r & 7u));

  uint4 o;
  if (isA) {
    const float* src = x + ((size_t)row << 12) + col;
    float4 f0 = *(const float4*)src;
    float4 f1 = *(const float4*)(src + 4);
    o.x = pack_bf16_rn(f0.x, f0.y); o.y = pack_bf16_rn(f0.z, f0.w);
    o.z = pack_bf16_rn(f1.x, f1.y); o.w = pack_bf16_rn(f1.z, f1.w);
    *(uint4*)((char*)wsA + (dst16 << 4)) = o;
  } else {
    const int* src = w + ((size_t)row << 12) + col;
    int4 i0 = *(const int4*)src;
    int4 i1 = *(const int4*)(src + 4);
    o.x = pack_bf16_int(i0.x, i0.y); o.y = pack_bf16_int(i0.z, i0.w);
    o.z = pack_bf16_int(i1.x, i1.y); o.w = pack_bf16_int(i1.z, i1.w);
    *(uint4*)((char*)wsB + (dst16 << 4)) = o;
  }
}

// ---------------- GEMM: 256x256 tile, 4-phase counted-vmcnt pipeline ----------------
// 512 threads = 8 waves (2 wr x 4 wc). Per-wave output 128x64 spread as
// rows: mh*128 + wr*64 + m*16, cols: nh*128 + wc*32 + n*16  (mh,nh select halves).
// LDS: 2 buffers x (A 32KB + B 32KB) = 128KB. K-tile t -> buf t&1.
// Per tile, 4 phases stage next tile's halves in order A-h0,B-h0,B-h1,A-h1 (2 loads each);
// phase needs: ph00{A-h0,B-h0} ph01{B-h1} ph10{A-h1} ph11{} -> uniform vmcnt(4), never 0.
__global__ __launch_bounds__(512, 2) void gemm_kernel(
    const u16* __restrict__ wsA, const u16* __restrict__ wsB,
    const float* __restrict__ scale, const float* __restrict__ bias,
    float* __restrict__ out) {
  __shared__ __attribute__((aligned(16))) char smem[131072];

  const int tid   = threadIdx.x;
  const int lane  = tid & 63;
  const int wid   = tid >> 6;   // 0..7
  const int wr    = wid >> 2;   // 0..1
  const int wc    = wid & 3;    // 0..3
  const int r16   = lane & 15;
  const int khalf = lane >> 4;  // 0..3

  // XCD-aware swizzle: 256 blocks, XCD x gets mt in {2x, 2x+1}
  const int bid = (int)blockIdx.x;
  const int swz = ((bid & 7) << 5) + (bid >> 3);
  const int mt = swz >> 4;   // 0..15
  const int nt = swz & 15;   // 0..15

  const char* gA = (const char*)wsA + ((size_t)mt << 21);  // mt*64 tiles * 32KB
  const char* gB = (const char*)wsB + ((size_t)nt << 21);

  // LDS read byte offsets (relative to the operand-half base)
  int aoff[4][2], boff[2][2];
#pragma unroll
  for (int kk = 0; kk < 2; ++kk) {
    int ch = ((kk * 4 + khalf) ^ (r16 & 7)) << 4;
#pragma unroll
    for (int m = 0; m < 4; ++m)
      aoff[m][kk] = ((wr << 6) + (m << 4) + r16) * 128 + ch;
#pragma unroll
    for (int n = 0; n < 2; ++n)
      boff[n][kk] = ((wc << 5) + (n << 4) + r16) * 128 + ch;
  }

  // staging offsets: half = 16KB = 512 thr x 2 rounds x 16B
  const int su = wid << 10;            // wave-uniform LDS part
  const int sl = su + lane * 16;       // per-lane global part

#define STAGE(gbase, dstbase)                                   \
  do {                                                          \
    gload16((gbase) + sl,        smem + (dstbase) + su);        \
    gload16((gbase) + sl + 8192, smem + (dstbase) + su + 8192); \
  } while (0)

  f32x4 acc[2][4][2][2];
#pragma unroll
  for (int mh = 0; mh < 2; ++mh)
#pragma unroll
    for (int m = 0; m < 4; ++m)
#pragma unroll
      for (int nh = 0; nh < 2; ++nh)
#pragma unroll
        for (int n = 0; n < 2; ++n)
          acc[mh][m][nh][n] = (f32x4){0.f, 0.f, 0.f, 0.f};

  bf16x8 af[4][2];        // current A-half fragments
  bf16x8 bfr[2][2][2];    // [bh][n][kk] both B-half fragments

  // Prologue: stage tile 0 into buf0 in order A-h0, B-h0, B-h1, A-h1
  STAGE(gA, 0);
  STAGE(gB, 32768);
  STAGE(gB + 16384, 49152);
  STAGE(gA + 16384, 16384);

  for (int t = 0; t < 64; ++t) {
    const int lb = (t & 1) << 16;
    const int sb = lb ^ 65536;
    const int ktn = (t + 1) & 63;  // t=63 wraps: harmless re-stage of tile 0
    const char* gAn = gA + ((size_t)ktn << 15);
    const char* gBn = gB + ((size_t)ktn << 15);

    // ---- phase (mh=0, nh=0): needs A-h0, B-h0 of tile t ----
    asm volatile("s_waitcnt vmcnt(4)" ::: "memory");
    __builtin_amdgcn_s_barrier();
    asm volatile("" ::: "memory");
    __builtin_amdgcn_sched_barrier(0);
#pragma unroll
    for (int m = 0; m < 4; ++m)
#pragma unroll
      for (int kk = 0; kk < 2; ++kk)
        af[m][kk] = *(const bf16x8*)(smem + lb + aoff[m][kk]);
#pragma unroll
    for (int n = 0; n < 2; ++n)
#pragma unroll
      for (int kk = 0; kk < 2; ++kk)
        bfr[0][n][kk] = *(const bf16x8*)(smem + lb + 32768 + boff[n][kk]);
    STAGE(gAn, sb);  // A-h0 of t+1
    __builtin_amdgcn_s_setprio(1);
#pragma unroll
    for (int m = 0; m < 4; ++m)
#pragma unroll
      for (int n = 0; n < 2; ++n)
#pragma unroll
        for (int kk = 0; kk < 2; ++kk)
          acc[0][m][0][n] = __builtin_amdgcn_mfma_f32_16x16x32_bf16(
              af[m][kk], bfr[0][n][kk], acc[0][m][0][n], 0, 0, 0);
    __builtin_amdgcn_s_setprio(0);

    // ---- phase (mh=0, nh=1): needs B-h1 of tile t ----
    asm volatile("s_waitcnt vmcnt(4)" ::: "memory");
    __builtin_amdgcn_s_barrier();
    asm volatile("" ::: "memory");
    __builtin_amdgcn_sched_barrier(0);
#pragma unroll
    for (int n = 0; n < 2; ++n)
#pragma unroll
      for (int kk = 0; kk < 2; ++kk)
        bfr[1][n][kk] = *(const bf16x8*)(smem + lb + 49152 + boff[n][kk]);
    STAGE(gBn, sb + 32768);  // B-h0 of t+1
    __builtin_amdgcn_s_setprio(1);
#pragma unroll
    for (int m = 0; m < 4; ++m)
#pragma unroll
      for (int n = 0; n < 2; ++n)
#pragma unroll
        for (int kk = 0; kk < 2; ++kk)
          acc[0][m][1][n] = __builtin_amdgcn_mfma_f32_16x16x32_bf16(
              af[m][kk], bfr[1][n][kk], acc[0][m][1][n], 0, 0, 0);
    __builtin_amdgcn_s_setprio(0);

    // ---- phase (mh=1, nh=0): needs A-h1 of tile t ----
    asm volatile("s_waitcnt vmcnt(4)" ::: "memory");
    __builtin_amdgcn_s_barrier();
    asm volatile("" ::: "memory");
    __builtin_amdgcn_sched_barrier(0);
#pragma unroll
    for (int m = 0; m < 4; ++m)
#pragma unroll
      for (int kk = 0; kk < 2; ++kk)
        af[m][kk] = *(const bf16x8*)(smem + lb + 16384 + aoff[m][kk]);
    STAGE(gBn + 16384, sb + 49152);  // B-h1 of t+1
    __builtin_amdgcn_s_setprio(1);
#pragma unroll
    for (int m = 0; m < 4; ++m)
#pragma unroll
      for (int n = 0; n < 2; ++n)
#pragma unroll
        for (int kk = 0; kk < 2; ++kk)
          acc[1][m][0][n] = __builtin_amdgcn_mfma_f32_16x16x32_bf16(
              af[m][kk], bfr[0][n][kk], acc[1][m][0][n], 0, 0, 0);
    __builtin_amdgcn_s_setprio(0);

    // ---- phase (mh=1, nh=1): pure register reuse, no reads, no barrier ----
    STAGE(gAn + 16384, sb + 16384);  // A-h1 of t+1
    __builtin_amdgcn_s_setprio(1);
#pragma unroll
    for (int m = 0; m < 4; ++m)
#pragma unroll
      for (int n = 0; n < 2; ++n)
#pragma unroll
        for (int kk = 0; kk < 2; ++kk)
          acc[1][m][1][n] = __builtin_amdgcn_mfma_f32_16x16x32_bf16(
              af[m][kk], bfr[1][n][kk], acc[1][m][1][n], 0, 0, 0);
    __builtin_amdgcn_s_setprio(0);
  }
#undef STAGE

  // Epilogue: out = acc * scale[col] + bias[col]
  // C/D: col = r16 (B-frag row), row-in-frag = khalf*4 + j (A-frag row).
#pragma unroll
  for (int nh = 0; nh < 2; ++nh)
#pragma unroll
    for (int n = 0; n < 2; ++n) {
      const int col = (nt << 8) + (nh << 7) + (wc << 5) + (n << 4) + r16;
      const float s  = scale[col];
      const float bb = bias[col];
#pragma unroll
      for (int mh = 0; mh < 2; ++mh)
#pragma unroll
        for (int m = 0; m < 4; ++m) {
          const int row0 = (mt << 8) + (mh << 7) + (wr << 6) + (m << 4) + (khalf << 2);
#pragma unroll
          for (int j = 0; j < 4; ++j)
            out[((size_t)(row0 + j) << 12) + col] = acc[mh][m][nh][n][j] * s + bb;
        }
    }
}

// ---------------- fallback (only if ws too small) ----------------
__global__ __launch_bounds__(256) void fallback_kernel(
    const float* __restrict__ x, const int* __restrict__ w,
    const float* __restrict__ scale, const float* __restrict__ bias,
    float* __restrict__ out) {
  size_t t = (size_t)blockIdx.x * 256 + threadIdx.x;
  if (t >= (size_t)M_DIM * N_DIM) return;
  int col = (int)(t & (N_DIM - 1));
  int row = (int)(t >> 12);
  const float* xr = x + ((size_t)row << 12);
  const int* wrow = w + ((size_t)col << 12);
  float acc = 0.f;
  for (int k = 0; k < K_DIM; k += 4) {
    float4 xv = *(const float4*)(xr + k);
    int4 wv = *(const int4*)(wrow + k);
    acc += xv.x * (float)wv.x;
    acc += xv.y * (float)wv.y;
    acc += xv.z * (float)wv.z;
    acc += xv.w * (float)wv.w;
  }
  out[t] = acc * scale[col] + bias[col];
}

// ---------------- launch ----------------
extern "C" void kernel_launch(void* const* d_in, const int* in_sizes, int n_in,
                              void* d_out, int out_size, void* d_ws, size_t ws_size,
                              hipStream_t stream) {
  const float* x     = (const float*)d_in[0];
  const int*   w     = (const int*)d_in[1];   // int8 values as int32
  const float* scale = (const float*)d_in[2];
  const float* bias  = (const float*)d_in[3];
  float*       out   = (float*)d_out;

  if (ws_size >= (size_t)64 * 1024 * 1024) {
    u16* wsA = (u16*)d_ws;
    u16* wsB = wsA + (size_t)M_DIM * K_DIM;  // +32MB

    convert_kernel<<<16384, 256, 0, stream>>>(x, w, wsA, wsB);
    gemm_kernel<<<256, 512, 0, stream>>>(wsA, wsB, scale, bias, out);
  } else {
    fallback_kernel<<<((size_t)M_DIM * N_DIM + 255) / 256, 256, 0, stream>>>(
        x, w, scale, bias, out);
  }
}